// Round 6
// baseline (98.045 us; speedup 1.0000x reference)
//
#include <hip/hip_runtime.h>

constexpr float ALPHA = 0.001f;
constexpr float BETA  = 0.001f;
constexpr int R   = 64;
constexpr int S   = 3;
constexpr int PFW = R * (1 + 2 * S); // 448 floats per pF row
constexpr int BSH  = 7;              // 128 pF rows/bucket = 229 KB L2 region
constexpr int MAXB = 800;            // >= 782 buckets
constexpr int SBLK = 256;            // hist/scatter block count
constexpr int RCAP = 1536;           // refine kernel LDS capacity (entries)

__device__ __forceinline__ float bfhi(unsigned u) {
    union { unsigned u; float f; } c; c.u = u & 0xffff0000u; return c.f;
}
__device__ __forceinline__ float bflo(unsigned u) {
    union { unsigned u; float f; } c; c.u = u << 16; return c.f;
}

// ---- M fp32 -> bf16 (RNE), 8 floats per thread ----
__global__ __launch_bounds__(256) void convM_kernel(const float* __restrict__ M,
                                                    uint4* __restrict__ Mb, int n8) {
    int idx = blockIdx.x * 256 + threadIdx.x;
    if (idx >= n8) return;
    const float4* src = reinterpret_cast<const float4*>(M);
    float4 a = src[2 * idx], b = src[2 * idx + 1];
    union { float f; unsigned u; } c;
    unsigned w[8];
    c.f = a.x; w[0] = c.u; c.f = a.y; w[1] = c.u; c.f = a.z; w[2] = c.u; c.f = a.w; w[3] = c.u;
    c.f = b.x; w[4] = c.u; c.f = b.y; w[5] = c.u; c.f = b.z; w[6] = c.u; c.f = b.w; w[7] = c.u;
    #pragma unroll
    for (int t = 0; t < 8; ++t) w[t] = (w[t] + 0x7fffu + ((w[t] >> 16) & 1u)) >> 16;
    Mb[idx] = make_uint4(w[0] | (w[1] << 16), w[2] | (w[3] << 16),
                         w[4] | (w[5] << 16), w[6] | (w[7] << 16));
}

// ---- hist: LDS-aggregated, fire-and-forget global merge ----
__global__ __launch_bounds__(256) void hist_kernel(const int* __restrict__ ijk, int B,
                                                   int chunk, int nb, int* __restrict__ hist) {
    __shared__ int lh[MAXB];
    for (int t = threadIdx.x; t < nb; t += blockDim.x) lh[t] = 0;
    __syncthreads();
    const int lo = blockIdx.x * chunk, hi = min(B, lo + chunk);
    for (int idx = lo + threadIdx.x; idx < hi; idx += blockDim.x)
        atomicAdd(&lh[ijk[3 * idx] >> BSH], 1);
    __syncthreads();
    for (int t = threadIdx.x; t < nb; t += blockDim.x)
        if (lh[t]) atomicAdd(&hist[t], lh[t]);
}

// ---- scan 782 -> offs (exclusive) + cursor init ----
__global__ __launch_bounds__(1024) void scan_kernel(const int* __restrict__ hist,
                                                    int* __restrict__ offs,
                                                    int* __restrict__ cursor, int nb) {
    __shared__ int buf[1024];
    int t = threadIdx.x;
    int own = (t < nb) ? hist[t] : 0;
    buf[t] = own;
    __syncthreads();
    for (int d = 1; d < 1024; d <<= 1) {
        int v = (t >= d) ? buf[t - d] : 0;
        __syncthreads();
        buf[t] += v;
        __syncthreads();
    }
    if (t < nb) { int e = buf[t] - own; offs[t] = e; cursor[t] = e; }
}

// ---- scatter: two-pass, per-(block,bucket) range reservation ----
__global__ __launch_bounds__(256) void scatter_kernel(const int* __restrict__ ijk, int B,
                                                      int chunk, int nb,
                                                      int* __restrict__ cursor,
                                                      int4* __restrict__ sorted) {
    __shared__ int cnt[MAXB];
    __shared__ int base[MAXB];
    __shared__ int rnk[MAXB];
    for (int t = threadIdx.x; t < nb; t += blockDim.x) { cnt[t] = 0; rnk[t] = 0; }
    __syncthreads();
    const int lo = blockIdx.x * chunk, hi = min(B, lo + chunk);
    for (int idx = lo + threadIdx.x; idx < hi; idx += blockDim.x)
        atomicAdd(&cnt[ijk[3 * idx] >> BSH], 1);
    __syncthreads();
    for (int t = threadIdx.x; t < nb; t += blockDim.x)
        if (cnt[t]) base[t] = atomicAdd(&cursor[t], cnt[t]);
    __syncthreads();
    for (int idx = lo + threadIdx.x; idx < hi; idx += blockDim.x) {
        const int i = ijk[3 * idx], j = ijk[3 * idx + 1], k = ijk[3 * idx + 2];
        const int bkt = i >> BSH;
        const int p = base[bkt] + atomicAdd(&rnk[bkt], 1);
        sorted[p] = make_int4(i, j, k, idx);
    }
}

// ---- refine: within each bucket, counting-sort by (i & 127) -> exact-i grouping.
//      In-place: each block exclusively owns [offs[bkt], end). ----
__global__ __launch_bounds__(256) void refine_kernel(int4* __restrict__ sorted,
                                                     const int* __restrict__ offs,
                                                     int B, int nb) {
    const int bkt = blockIdx.x;
    const int start = offs[bkt];
    const int end = (bkt + 1 < nb) ? offs[bkt + 1] : B;
    const int count = end - start;
    if (count <= 1 || count > RCAP) return;   // oversize bucket: leave bucket-ordered

    __shared__ int4 ent[RCAP];
    __shared__ int cnt[128];
    __shared__ int base[128];

    for (int t = threadIdx.x; t < 128; t += 256) cnt[t] = 0;
    __syncthreads();
    for (int t = threadIdx.x; t < count; t += 256) {
        int4 e = sorted[start + t];
        ent[t] = e;
        atomicAdd(&cnt[e.x & 127], 1);
    }
    __syncthreads();
    if (threadIdx.x == 0) {
        int run = 0;
        #pragma unroll 4
        for (int t = 0; t < 128; ++t) { base[t] = run; run += cnt[t]; }
    }
    __syncthreads();
    for (int t = threadIdx.x; t < 128; t += 256) cnt[t] = 0;
    __syncthreads();
    for (int t = threadIdx.x; t < count; t += 256) {
        int4 e = ent[t];
        const int key = e.x & 127;
        const int p = base[key] + atomicAdd(&cnt[key], 1);
        sorted[start + p] = e;
    }
}

// ---- main: 16 lanes per b, 1 b per group, exact-i-ordered, XCD-chunked ----
__global__ __launch_bounds__(256) void mf_if_kernel(
    const float* __restrict__ pF,
    const float* __restrict__ M,      // fp32 fallback
    const uint2* __restrict__ Mb,     // bf16 packed (16 uint2 per row), may be null
    const int4*  __restrict__ sorted, // may be null -> identity order via ijk
    const int*   __restrict__ ijk,
    float* __restrict__ out,
    int B, int nwg)
{
    // bijective XCD-chunked swizzle (m204)
    const int orig = blockIdx.x;
    const int q = nwg >> 3, r = nwg & 7;
    const int xcd = orig & 7;
    const int wgid = (xcd < r ? xcd * (q + 1) : r * (q + 1) + (xcd - r) * q) + (orig >> 3);

    const int sub = threadIdx.x & 15;
    const long pos = (long)wgid * 16 + (threadIdx.x >> 4);
    if (pos >= B) return;

    int4 s;
    if (sorted) s = sorted[pos];
    else s = make_int4(ijk[3 * pos], ijk[3 * pos + 1], ijk[3 * pos + 2], (int)pos);

    const int kc = (s.z < 0) ? 0 : s.z;

    const float4* pFi = reinterpret_cast<const float4*>(pF + (size_t)s.x * PFW);

    float4 mj, mk;
    if (Mb) {
        const uint2 uj = Mb[(size_t)s.y * 16 + sub];
        const uint2 uk = Mb[(size_t)kc  * 16 + sub];
        mj = make_float4(bflo(uj.x), bfhi(uj.x), bflo(uj.y), bfhi(uj.y));
        mk = make_float4(bflo(uk.x), bfhi(uk.x), bflo(uk.y), bfhi(uk.y));
    } else {
        mj = reinterpret_cast<const float4*>(M + (size_t)s.y * R)[sub];
        mk = reinterpret_cast<const float4*>(M + (size_t)kc  * R)[sub];
    }

    const float4 pi = pFi[sub];
    float p = pi.x * mj.x + pi.y * mj.y + pi.z * mj.z + pi.w * mj.w;

    const float4 v0 = pFi[16 + 3 * sub + 0];
    const float4 v1 = pFi[16 + 3 * sub + 1];
    const float4 v2 = pFi[16 + 3 * sub + 2];
    float a0 = v0.x * mj.x + v0.w * mj.y + v1.z * mj.z + v2.y * mj.w;
    float a1 = v0.y * mj.x + v1.x * mj.y + v1.w * mj.z + v2.z * mj.w;
    float a2 = v0.z * mj.x + v1.y * mj.y + v2.x * mj.z + v2.w * mj.w;

    const float4 w0 = pFi[64 + 3 * sub + 0];
    const float4 w1 = pFi[64 + 3 * sub + 1];
    const float4 w2 = pFi[64 + 3 * sub + 2];
    float g0 = w0.x * mk.x + w0.w * mk.y + w1.z * mk.z + w2.y * mk.w;
    float g1 = w0.y * mk.x + w1.x * mk.y + w1.w * mk.z + w2.z * mk.w;
    float g2 = w0.z * mk.x + w1.y * mk.y + w2.x * mk.z + w2.w * mk.w;

    #pragma unroll
    for (int off = 8; off >= 1; off >>= 1) {
        p  += __shfl_xor(p,  off);
        a0 += __shfl_xor(a0, off);
        a1 += __shfl_xor(a1, off);
        a2 += __shfl_xor(a2, off);
        g0 += __shfl_xor(g0, off);
        g1 += __shfl_xor(g1, off);
        g2 += __shfl_xor(g2, off);
    }

    if (sub == 0) {
        const float mfm = (s.z != -1)
            ? (BETA * BETA) * (a0 * g0 + a1 * g1 + a2 * g2) : 0.0f;
        out[s.w] = ALPHA * p + mfm;
    }
}

extern "C" void kernel_launch(void* const* d_in, const int* in_sizes, int n_in,
                              void* d_out, int out_size, void* d_ws, size_t ws_size,
                              hipStream_t stream) {
    const float* pF  = (const float*)d_in[0];
    const float* M   = (const float*)d_in[1];
    const int*   ijk = (const int*)d_in[2];
    float* out = (float*)d_out;

    const int B   = in_sizes[2] / 3;     // 500000
    const int N_P = in_sizes[0] / PFW;   // 100000
    const int N_M = in_sizes[1] / R;     // 100000
    const int nb  = (N_P + (1 << BSH) - 1) >> BSH; // 782

    // ws layout: hist[1024] offs[1024] cursor[1024] | pad to 16KB | sorted int4[B] | Mb bf16[N_M*R]
    const size_t sorted_off = 16 * 1024;
    const size_t mb_off     = sorted_off + (size_t)B * sizeof(int4);
    const size_t need_sort  = mb_off;
    const size_t need_full  = mb_off + (size_t)N_M * R * 2;

    int4*  sorted = nullptr;
    uint2* Mb     = nullptr;

    if (nb <= MAXB && ws_size >= need_sort) {
        int* hist   = (int*)d_ws;
        int* offs   = hist + 1024;
        int* cursor = hist + 2048;
        sorted = (int4*)((char*)d_ws + sorted_off);
        const int chunk = (B + SBLK - 1) / SBLK;

        hipMemsetAsync(hist, 0, 1024 * sizeof(int), stream);
        hist_kernel<<<SBLK, 256, 0, stream>>>(ijk, B, chunk, nb, hist);
        scan_kernel<<<1, 1024, 0, stream>>>(hist, offs, cursor, nb);
        scatter_kernel<<<SBLK, 256, 0, stream>>>(ijk, B, chunk, nb, cursor, sorted);
        refine_kernel<<<nb, 256, 0, stream>>>(sorted, offs, B, nb);
    }
    if (ws_size >= need_full) {
        Mb = (uint2*)((char*)d_ws + mb_off);
        const int n8 = N_M * R / 8;
        convM_kernel<<<(n8 + 255) / 256, 256, 0, stream>>>(M, (uint4*)Mb, n8);
    }

    const int nwg = (B + 15) / 16;   // 16 b's per 256-thread block
    mf_if_kernel<<<nwg, 256, 0, stream>>>(pF, M, Mb, sorted, ijk, out, B, nwg);
}